// Round 6
// baseline (794.858 us; speedup 1.0000x reference)
//
#include <hip/hip_runtime.h>
#include <math.h>

#define NODES 100000
#define EDGES 1600000
#define DH 128
#define DOUT 40

// ---- CSR bucket-sort geometry ----
#define BSHIFT 9
#define NBUCK 196                 // ceil(NODES/512)
#define HB 200                    // histogram blocks
#define EPB 8000                  // edges per histogram block
#define GH (NBUCK * HB)           // 39200
#define NHS ((GH + 511) / 512)    // 77

typedef __attribute__((ext_vector_type(8))) short bf16x8;
typedef __attribute__((ext_vector_type(4))) float f32x4;

__device__ inline ushort bfh(float f) {           // f32 -> bf16 bits (RNE)
    uint u = __float_as_uint(f);
    return (ushort)((u + 0x7FFFu + ((u >> 16) & 1u)) >> 16);
}
__device__ inline float bff(ushort h) { return __uint_as_float(((uint)h) << 16); }

// ================= CSR build: no global atomics =================

__global__ __launch_bounds__(256) void hist1_kernel(const int* __restrict__ dst,
                                                    uint* __restrict__ ghist) {
    __shared__ uint h[NBUCK];
    int t = threadIdx.x;
    if (t < NBUCK) h[t] = 0;
    __syncthreads();
    int e0 = blockIdx.x * EPB;
    for (int e = e0 + t; e < e0 + EPB; e += 256)
        atomicAdd(&h[((uint)dst[e]) >> BSHIFT], 1u);
    __syncthreads();
    if (t < NBUCK) ghist[t * HB + blockIdx.x] = h[t];   // bucket-major
}

__global__ __launch_bounds__(512) void hs1_kernel(const uint* __restrict__ ghist,
                                                  uint* __restrict__ hpart) {
    __shared__ uint buf[512];
    int i = blockIdx.x * 512 + threadIdx.x;
    buf[threadIdx.x] = (i < GH) ? ghist[i] : 0;
    __syncthreads();
    for (int off = 256; off; off >>= 1) {
        if (threadIdx.x < off) buf[threadIdx.x] += buf[threadIdx.x + off];
        __syncthreads();
    }
    if (threadIdx.x == 0) hpart[blockIdx.x] = buf[0];
}

__global__ __launch_bounds__(128) void hs2_kernel(const uint* __restrict__ hpart,
                                                  uint* __restrict__ hpoff,
                                                  int* __restrict__ rowptr,
                                                  int* __restrict__ bucket_base) {
    __shared__ uint buf[128];
    uint v = (threadIdx.x < NHS) ? hpart[threadIdx.x] : 0;
    buf[threadIdx.x] = v;
    __syncthreads();
    for (int off = 1; off < 128; off <<= 1) {
        uint tv = (threadIdx.x >= off) ? buf[threadIdx.x - off] : 0;
        __syncthreads();
        buf[threadIdx.x] += tv;
        __syncthreads();
    }
    if (threadIdx.x < NHS) hpoff[threadIdx.x] = buf[threadIdx.x] - v;   // exclusive
    if (threadIdx.x == 0) { rowptr[NODES] = EDGES; bucket_base[NBUCK] = EDGES; }
}

__global__ __launch_bounds__(512) void hs3_kernel(uint* __restrict__ ghist,
                                                  const uint* __restrict__ hpoff,
                                                  int* __restrict__ bucket_base) {
    __shared__ uint buf[512];
    int i = blockIdx.x * 512 + threadIdx.x;
    uint v = (i < GH) ? ghist[i] : 0;
    buf[threadIdx.x] = v;
    __syncthreads();
    for (int off = 1; off < 512; off <<= 1) {
        uint tv = (threadIdx.x >= off) ? buf[threadIdx.x - off] : 0;
        __syncthreads();
        buf[threadIdx.x] += tv;
        __syncthreads();
    }
    if (i < GH) {
        uint ex = hpoff[blockIdx.x] + buf[threadIdx.x] - v;
        ghist[i] = ex;
        if (i % HB == 0) bucket_base[i / HB] = (int)ex;
    }
}

__global__ __launch_bounds__(256) void scatter1_kernel(const int* __restrict__ src,
                                                       const int* __restrict__ dst,
                                                       const uint* __restrict__ ghist,
                                                       uint2* __restrict__ ebuf) {
    __shared__ uint cur[NBUCK];
    int t = threadIdx.x;
    if (t < NBUCK) cur[t] = ghist[t * HB + blockIdx.x];
    __syncthreads();
    int e0 = blockIdx.x * EPB;
    for (int e = e0 + t; e < e0 + EPB; e += 256) {
        uint d = (uint)dst[e];
        uint s = (uint)src[e];
        uint pos = atomicAdd(&cur[d >> BSHIFT], 1u);
        ebuf[pos] = make_uint2(d, s);
    }
}

__global__ __launch_bounds__(256) void csr2_kernel(const uint2* __restrict__ ebuf,
                                                   const int* __restrict__ bucket_base,
                                                   int* __restrict__ rowptr,
                                                   int* __restrict__ col) {
    __shared__ uint h[512];
    __shared__ uint cur[512];
    __shared__ uint buf[256];
    int b = blockIdx.x;
    int t = threadIdx.x;
    int seg0 = bucket_base[b];
    int seg1 = bucket_base[b + 1];
    h[t] = 0; h[t + 256] = 0;
    __syncthreads();
    uint nbase = (uint)b << BSHIFT;
    for (int e = seg0 + t; e < seg1; e += 256)
        atomicAdd(&h[ebuf[e].x - nbase], 1u);
    __syncthreads();
    uint s0 = h[2 * t], s1 = h[2 * t + 1];
    uint pair = s0 + s1;
    buf[t] = pair;
    __syncthreads();
    for (int off = 1; off < 256; off <<= 1) {
        uint tv = (t >= off) ? buf[t - off] : 0;
        __syncthreads();
        buf[t] += tv;
        __syncthreads();
    }
    uint epre = buf[t] - pair;
    cur[2 * t]     = seg0 + epre;
    cur[2 * t + 1] = seg0 + epre + s0;
    int node0 = (int)nbase + 2 * t;
    if (node0 < NODES)     rowptr[node0]     = seg0 + epre;
    if (node0 + 1 < NODES) rowptr[node0 + 1] = seg0 + epre + s0;
    __syncthreads();
    for (int e = seg0 + t; e < seg1; e += 256) {
        uint2 p = ebuf[e];
        uint pos = atomicAdd(&cur[p.x - nbase], 1u);
        col[pos] = (int)p.y;
    }
}

// ================= combined weight split =================
__global__ void wsplit_all_kernel(const float* __restrict__ Ws1, const float* __restrict__ Wn1,
                                  const float* __restrict__ Ws2, const float* __restrict__ Wn2,
                                  const float* __restrict__ Ws3, const float* __restrict__ Wn3,
                                  ushort* __restrict__ Wh, ushort* __restrict__ Wl) {
    int i = blockIdx.x * blockDim.x + threadIdx.x;   // 0 .. 77823
    if (i >= 4 * 16384 + 2 * 6144) return;
    float v;
    if (i < 65536) {
        int which = i >> 14, j = i & 16383;
        const float* W = (which == 0) ? Ws1 : (which == 1) ? Wn1 : (which == 2) ? Ws2 : Wn2;
        v = W[j];
    } else {
        int i2 = i - 65536;
        int which = (i2 >= 6144) ? 1 : 0;
        int j = i2 - which * 6144;
        int n = j >> 7, k = j & 127;
        const float* W = which ? Wn3 : Ws3;
        v = (n < DOUT) ? W[n * 128 + k] : 0.f;
    }
    ushort h = bfh(v);
    Wh[i] = h;
    Wl[i] = bfh(v - bff(h));
}

// feat f32 -> hi/lo bf16 pair
__global__ void fsplit_kernel(const float* __restrict__ f, ushort* __restrict__ xh,
                              ushort* __restrict__ xl) {
    int i = blockIdx.x * blockDim.x + threadIdx.x;   // per float4
    float4 v = *reinterpret_cast<const float4*>(f + (size_t)i * 4);
    ushort4 h, l;
    h.x = bfh(v.x); h.y = bfh(v.y); h.z = bfh(v.z); h.w = bfh(v.w);
    l.x = bfh(v.x - bff(h.x)); l.y = bfh(v.y - bff(h.y));
    l.z = bfh(v.z - bff(h.z)); l.w = bfh(v.w - bff(h.w));
    *reinterpret_cast<ushort4*>(xh + (size_t)i * 4) = h;
    *reinterpret_cast<ushort4*>(xl + (size_t)i * 4) = l;
}

// ================= fused gather + dual-GEMM + BN-partials (layers 1,2) =================
// Per block: 32 rows. Stage xh/xl tiles; gather neighbor means of xh into LDS (hi/lo);
// 6-MFMA split-precision accumulate; write pre-BN f32 h; emit per-block BN column partials.
#define MFMA(a, b, c) __builtin_amdgcn_mfma_f32_16x16x32_bf16(a, b, c, 0, 0, 0)

__global__ __launch_bounds__(256) void gemm12_fused(
    const ushort* __restrict__ xh, const ushort* __restrict__ xl,
    const int* __restrict__ rowptr, const int* __restrict__ col,
    const ushort* __restrict__ Wsh, const ushort* __restrict__ Wsl,
    const ushort* __restrict__ Wnh, const ushort* __restrict__ Wnl,
    float* __restrict__ out, float* __restrict__ partials, float* __restrict__ stat0) {
    if (blockIdx.x == 0) stat0[threadIdx.x] = 0.f;   // zero stats[256] for bnred
    __shared__ ushort xh_s[32 * 128], xl_s[32 * 128], ah_s[32 * 128], al_s[32 * 128];
    int t = threadIdx.x;
    int row0 = blockIdx.x * 32;
    // ---- stage self rows (pure copy, pre-split) ----
#pragma unroll
    for (int i = 0; i < 2; ++i) {
        int f = t + i * 256;            // 512 chunks of 8 shorts
        int r = f >> 4;
        int c0 = (f & 15) * 8;
        int cs = c0 ^ ((r & 7) << 3);
        *reinterpret_cast<uint4*>(&xh_s[r * 128 + cs]) =
            *reinterpret_cast<const uint4*>(xh + (size_t)(row0 + r) * 128 + c0);
        *reinterpret_cast<uint4*>(&xl_s[r * 128 + cs]) =
            *reinterpret_cast<const uint4*>(xl + (size_t)(row0 + r) * 128 + c0);
    }
    // ---- gather neighbor means into LDS (each wave: 8 nodes) ----
    int w = t >> 6;
    int l = t & 63;
    int g = l >> 4;          // neighbor slot 0..3
    int sub = l & 15;        // dim chunk [sub*8, sub*8+8)
#pragma unroll
    for (int i = 0; i < 8; ++i) {
        int r = w * 8 + i;
        int node = row0 + r;
        int p0 = rowptr[node], p1 = rowptr[node + 1];
        float acc[8] = {};
        for (int p = p0 + g; p < p1; p += 4) {
            int s = col[p];
            uint4 v = *reinterpret_cast<const uint4*>(xh + (size_t)s * 128 + sub * 8);
            acc[0] += bff((ushort)(v.x & 0xffff)); acc[1] += bff((ushort)(v.x >> 16));
            acc[2] += bff((ushort)(v.y & 0xffff)); acc[3] += bff((ushort)(v.y >> 16));
            acc[4] += bff((ushort)(v.z & 0xffff)); acc[5] += bff((ushort)(v.z >> 16));
            acc[6] += bff((ushort)(v.w & 0xffff)); acc[7] += bff((ushort)(v.w >> 16));
        }
#pragma unroll
        for (int j = 0; j < 8; ++j) {
            acc[j] += __shfl_xor(acc[j], 16, 64);
            acc[j] += __shfl_xor(acc[j], 32, 64);
        }
        if (l < 16) {
            float rd = 1.0f / fmaxf((float)(p1 - p0), 1.0f);
            bf16x8 hi, lo;
#pragma unroll
            for (int j = 0; j < 8; ++j) {
                float m = acc[j] * rd;
                ushort hb = bfh(m);
                hi[j] = (short)hb;
                lo[j] = (short)bfh(m - bff(hb));
            }
            int cs = (sub * 8) ^ ((r & 7) << 3);
            *reinterpret_cast<bf16x8*>(&ah_s[r * 128 + cs]) = hi;
            *reinterpret_cast<bf16x8*>(&al_s[r * 128 + cs]) = lo;
        }
    }
    __syncthreads();
    // ---- MFMA phase ----
    int lr = l & 15;
    int kq = (l >> 4) * 8;
    int n0 = w * 32;
    f32x4 acc[2][2] = {};
    for (int kk = 0; kk < 4; ++kk) {
        int kf = kk * 32 + kq;
        bf16x8 a_xh[2], a_xl[2], a_ah[2], a_al[2];
#pragma unroll
        for (int rt = 0; rt < 2; ++rt) {
            int r = rt * 16 + lr;
            int ks = kf ^ ((r & 7) << 3);
            a_xh[rt] = *reinterpret_cast<const bf16x8*>(&xh_s[r * 128 + ks]);
            a_xl[rt] = *reinterpret_cast<const bf16x8*>(&xl_s[r * 128 + ks]);
            a_ah[rt] = *reinterpret_cast<const bf16x8*>(&ah_s[r * 128 + ks]);
            a_al[rt] = *reinterpret_cast<const bf16x8*>(&al_s[r * 128 + ks]);
        }
#pragma unroll
        for (int ct = 0; ct < 2; ++ct) {
            size_t wo = (size_t)(n0 + ct * 16 + lr) * 128 + kf;
            bf16x8 bsh = *reinterpret_cast<const bf16x8*>(Wsh + wo);
            bf16x8 bsl = *reinterpret_cast<const bf16x8*>(Wsl + wo);
            bf16x8 bnh = *reinterpret_cast<const bf16x8*>(Wnh + wo);
            bf16x8 bnl = *reinterpret_cast<const bf16x8*>(Wnl + wo);
#pragma unroll
            for (int rt = 0; rt < 2; ++rt) {
                acc[rt][ct] = MFMA(a_xh[rt], bsh, acc[rt][ct]);
                acc[rt][ct] = MFMA(a_xh[rt], bsl, acc[rt][ct]);
                acc[rt][ct] = MFMA(a_xl[rt], bsh, acc[rt][ct]);
                acc[rt][ct] = MFMA(a_ah[rt], bnh, acc[rt][ct]);
                acc[rt][ct] = MFMA(a_ah[rt], bnl, acc[rt][ct]);
                acc[rt][ct] = MFMA(a_al[rt], bnh, acc[rt][ct]);
            }
        }
    }
    int dr = (l >> 4) * 4;
#pragma unroll
    for (int rt = 0; rt < 2; ++rt)
#pragma unroll
        for (int ct = 0; ct < 2; ++ct)
#pragma unroll
            for (int j = 0; j < 4; ++j)
                out[(size_t)(row0 + rt * 16 + dr + j) * 128 + n0 + ct * 16 + lr] = acc[rt][ct][j];
    // ---- BN column partials from registers (sum over this block's 32 rows) ----
    float s0 = 0.f, q0 = 0.f, s1 = 0.f, q1 = 0.f;
#pragma unroll
    for (int rt = 0; rt < 2; ++rt)
#pragma unroll
        for (int j = 0; j < 4; ++j) {
            float v0 = acc[rt][0][j], v1 = acc[rt][1][j];
            s0 += v0; q0 += v0 * v0;
            s1 += v1; q1 += v1 * v1;
        }
    s0 += __shfl_xor(s0, 16, 64); s0 += __shfl_xor(s0, 32, 64);
    q0 += __shfl_xor(q0, 16, 64); q0 += __shfl_xor(q0, 32, 64);
    s1 += __shfl_xor(s1, 16, 64); s1 += __shfl_xor(s1, 32, 64);
    q1 += __shfl_xor(q1, 16, 64); q1 += __shfl_xor(q1, 32, 64);
    if (l < 16) {
        float* pb = partials + (size_t)blockIdx.x * 256;
        pb[n0 + lr] = s0;
        pb[n0 + 16 + lr] = s1;
        pb[128 + n0 + lr] = q0;
        pb[128 + n0 + 16 + lr] = q1;
    }
}

// reduce per-block partials -> stats[256] (sums[128] ++ sumsq[128])
__global__ __launch_bounds__(256) void bnred_kernel(const float* __restrict__ partials,
                                                    float* __restrict__ stats, int nblk) {
    float s = 0.f;
    for (int b = blockIdx.x; b < nblk; b += gridDim.x)
        s += partials[(size_t)b * 256 + threadIdx.x];
    atomicAdd(&stats[threadIdx.x], s);
}

// fused BN finalize+apply+relu: reads pre-BN f32, writes hi/lo bf16 pair
__global__ void bn_apply_kernel(const float* __restrict__ h, ushort* __restrict__ xh,
                                ushort* __restrict__ xl, const float* __restrict__ stats,
                                const float* __restrict__ gamma, const float* __restrict__ beta) {
    long long t = (long long)blockIdx.x * blockDim.x + threadIdx.x;
    if (t >= (long long)NODES * 32) return;
    int j4 = ((int)(t & 31)) * 4;
    size_t off = (size_t)(t >> 5) * 128 + j4;
    float4 v = *reinterpret_cast<const float4*>(h + off);
    float4 s4 = *reinterpret_cast<const float4*>(stats + j4);
    float4 q4 = *reinterpret_cast<const float4*>(stats + 128 + j4);
    float4 g4 = *reinterpret_cast<const float4*>(gamma + j4);
    float4 be4 = *reinterpret_cast<const float4*>(beta + j4);
    const float inv = 1.0f / NODES;
    float m, var, a;
    m = s4.x * inv; var = q4.x * inv - m * m; a = g4.x * rsqrtf(var + 1e-5f);
    v.x = fmaxf(v.x * a + (be4.x - m * a), 0.f);
    m = s4.y * inv; var = q4.y * inv - m * m; a = g4.y * rsqrtf(var + 1e-5f);
    v.y = fmaxf(v.y * a + (be4.y - m * a), 0.f);
    m = s4.z * inv; var = q4.z * inv - m * m; a = g4.z * rsqrtf(var + 1e-5f);
    v.z = fmaxf(v.z * a + (be4.z - m * a), 0.f);
    m = s4.w * inv; var = q4.w * inv - m * m; a = g4.w * rsqrtf(var + 1e-5f);
    v.w = fmaxf(v.w * a + (be4.w - m * a), 0.f);
    ushort4 hh, ll;
    hh.x = bfh(v.x); hh.y = bfh(v.y); hh.z = bfh(v.z); hh.w = bfh(v.w);
    ll.x = bfh(v.x - bff(hh.x)); ll.y = bfh(v.y - bff(hh.y));
    ll.z = bfh(v.z - bff(hh.z)); ll.w = bfh(v.w - bff(hh.w));
    *reinterpret_cast<ushort4*>(xh + off) = hh;
    *reinterpret_cast<ushort4*>(xl + off) = ll;
}

// ================= fused gather + GEMM3 + log-softmax =================
__global__ __launch_bounds__(256) void gemm3_fused(
    const ushort* __restrict__ xh, const ushort* __restrict__ xl,
    const int* __restrict__ rowptr, const int* __restrict__ col,
    const ushort* __restrict__ Wsh, const ushort* __restrict__ Wsl,
    const ushort* __restrict__ Wnh, const ushort* __restrict__ Wnl,
    float* __restrict__ out) {
    __shared__ ushort xh_s[64 * 128], xl_s[64 * 128], ah_s[64 * 128], al_s[64 * 128];
    int t = threadIdx.x;
    int row0 = blockIdx.x * 64;
#pragma unroll
    for (int i = 0; i < 4; ++i) {
        int f = t + i * 256;            // 1024 chunks of 8 shorts
        int r = f >> 4;
        int c0 = (f & 15) * 8;
        int cs = c0 ^ ((r & 7) << 3);
        int rr = row0 + r; if (rr >= NODES) rr = NODES - 1;
        *reinterpret_cast<uint4*>(&xh_s[r * 128 + cs]) =
            *reinterpret_cast<const uint4*>(xh + (size_t)rr * 128 + c0);
        *reinterpret_cast<uint4*>(&xl_s[r * 128 + cs]) =
            *reinterpret_cast<const uint4*>(xl + (size_t)rr * 128 + c0);
    }
    int w = t >> 6;
    int l = t & 63;
    int g = l >> 4;
    int sub = l & 15;
#pragma unroll
    for (int i = 0; i < 16; ++i) {
        int r = w * 16 + i;
        int node = row0 + r; if (node >= NODES) node = NODES - 1;
        int p0 = rowptr[node], p1 = rowptr[node + 1];
        float acc[8] = {};
        for (int p = p0 + g; p < p1; p += 4) {
            int s = col[p];
            uint4 v = *reinterpret_cast<const uint4*>(xh + (size_t)s * 128 + sub * 8);
            acc[0] += bff((ushort)(v.x & 0xffff)); acc[1] += bff((ushort)(v.x >> 16));
            acc[2] += bff((ushort)(v.y & 0xffff)); acc[3] += bff((ushort)(v.y >> 16));
            acc[4] += bff((ushort)(v.z & 0xffff)); acc[5] += bff((ushort)(v.z >> 16));
            acc[6] += bff((ushort)(v.w & 0xffff)); acc[7] += bff((ushort)(v.w >> 16));
        }
#pragma unroll
        for (int j = 0; j < 8; ++j) {
            acc[j] += __shfl_xor(acc[j], 16, 64);
            acc[j] += __shfl_xor(acc[j], 32, 64);
        }
        if (l < 16) {
            float rd = 1.0f / fmaxf((float)(p1 - p0), 1.0f);
            bf16x8 hi, lo;
#pragma unroll
            for (int j = 0; j < 8; ++j) {
                float m = acc[j] * rd;
                ushort hb = bfh(m);
                hi[j] = (short)hb;
                lo[j] = (short)bfh(m - bff(hb));
            }
            int cs = (sub * 8) ^ ((r & 7) << 3);
            *reinterpret_cast<bf16x8*>(&ah_s[r * 128 + cs]) = hi;
            *reinterpret_cast<bf16x8*>(&al_s[r * 128 + cs]) = lo;
        }
    }
    __syncthreads();
    int lr = l & 15;
    int kq = (l >> 4) * 8;
    f32x4 acc[3] = {};
    for (int kk = 0; kk < 4; ++kk) {
        int kf = kk * 32 + kq;
        int r = w * 16 + lr;
        int ks = kf ^ ((r & 7) << 3);
        bf16x8 a_xh = *reinterpret_cast<const bf16x8*>(&xh_s[r * 128 + ks]);
        bf16x8 a_xl = *reinterpret_cast<const bf16x8*>(&xl_s[r * 128 + ks]);
        bf16x8 a_ah = *reinterpret_cast<const bf16x8*>(&ah_s[r * 128 + ks]);
        bf16x8 a_al = *reinterpret_cast<const bf16x8*>(&al_s[r * 128 + ks]);
#pragma unroll
        for (int ct = 0; ct < 3; ++ct) {
            size_t wo = (size_t)(ct * 16 + lr) * 128 + kf;
            bf16x8 bsh = *reinterpret_cast<const bf16x8*>(Wsh + wo);
            bf16x8 bsl = *reinterpret_cast<const bf16x8*>(Wsl + wo);
            bf16x8 bnh = *reinterpret_cast<const bf16x8*>(Wnh + wo);
            bf16x8 bnl = *reinterpret_cast<const bf16x8*>(Wnl + wo);
            acc[ct] = MFMA(a_xh, bsh, acc[ct]);
            acc[ct] = MFMA(a_xh, bsl, acc[ct]);
            acc[ct] = MFMA(a_xl, bsh, acc[ct]);
            acc[ct] = MFMA(a_ah, bnh, acc[ct]);
            acc[ct] = MFMA(a_ah, bnl, acc[ct]);
            acc[ct] = MFMA(a_al, bnh, acc[ct]);
        }
    }
    int dr = (l >> 4) * 4;
#pragma unroll
    for (int j = 0; j < 4; ++j) {
        float v0 = acc[0][j], v1 = acc[1][j];
        float v2 = (lr < 8) ? acc[2][j] : -INFINITY;
        float m = fmaxf(v0, fmaxf(v1, v2));
#pragma unroll
        for (int o = 8; o; o >>= 1) m = fmaxf(m, __shfl_xor(m, o, 16));
        float e = expf(v0 - m) + expf(v1 - m) + ((lr < 8) ? expf(v2 - m) : 0.f);
#pragma unroll
        for (int o = 8; o; o >>= 1) e += __shfl_xor(e, o, 16);
        float lse = m + logf(e);
        int row = row0 + w * 16 + dr + j;
        if (row < NODES) {
            out[(size_t)row * DOUT + lr] = v0 - lse;
            out[(size_t)row * DOUT + 16 + lr] = v1 - lse;
            if (lr < 8) out[(size_t)row * DOUT + 32 + lr] = acc[2][j] - lse;
        }
    }
}

extern "C" void kernel_launch(void* const* d_in, const int* in_sizes, int n_in,
                              void* d_out, int out_size, void* d_ws, size_t ws_size,
                              hipStream_t stream) {
    const float* feat   = (const float*)d_in[0];
    const float* Ws1    = (const float*)d_in[1];
    const float* Wn1    = (const float*)d_in[2];
    const float* gamma1 = (const float*)d_in[3];
    const float* beta1  = (const float*)d_in[4];
    const float* Ws2    = (const float*)d_in[5];
    const float* Wn2    = (const float*)d_in[6];
    const float* gamma2 = (const float*)d_in[7];
    const float* beta2  = (const float*)d_in[8];
    const float* Ws3    = (const float*)d_in[9];
    const float* Wn3    = (const float*)d_in[10];
    const int*   src    = (const int*)d_in[11];
    const int*   dst    = (const int*)d_in[12];
    float* out = (float*)d_out;

    float* ws = (float*)d_ws;
    const size_t NF = (size_t)NODES * 128;
    float* xbuf = ws;                       // N*128 f32 pre-BN (aliases ebuf during CSR build)
    float* stats = ws + NF;                 // 256 f32: sums[128] ++ sumsq[128]
    float* partials = stats + 256;          // 3125*256 f32
    ushort* xh = (ushort*)(partials + 3125 * 256);   // N*128 bf16 hi
    ushort* xl = xh + NF;                   // N*128 bf16 lo
    ushort* Wh = xl + NF;                   // 77824
    ushort* Wl = Wh + 77824;
    int* rowptr = (int*)(Wl + 77824);       // N+1
    uint* ghist = (uint*)(rowptr + NODES + 1);
    uint* hpart = ghist + GH;               // 128
    uint* hpoff = hpart + 128;              // 128
    int* bucket_base = (int*)(hpoff + 128); // NBUCK+1
    int* col    = bucket_base + NBUCK + 1;  // E
    uint2* ebuf = (uint2*)xbuf;             // E uint2 = 12.8MB, dead before gemm L1

    ushort* Wsh1 = Wh;           ushort* Wsl1 = Wl;
    ushort* Wnh1 = Wh + 16384;   ushort* Wnl1 = Wl + 16384;
    ushort* Wsh2 = Wh + 32768;   ushort* Wsl2 = Wl + 32768;
    ushort* Wnh2 = Wh + 49152;   ushort* Wnl2 = Wl + 49152;
    ushort* Wsh3 = Wh + 65536;   ushort* Wsl3 = Wl + 65536;
    ushort* Wnh3 = Wh + 71680;   ushort* Wnl3 = Wl + 71680;

    const int GEMM_GRID  = NODES / 32;           // 3125
    const int GEMM3_GRID = (NODES + 63) / 64;    // 1563

    // ---- CSR build: bucket sort, LDS atomics only ----
    hist1_kernel<<<HB, 256, 0, stream>>>(dst, ghist);
    hs1_kernel<<<NHS, 512, 0, stream>>>(ghist, hpart);
    hs2_kernel<<<1, 128, 0, stream>>>(hpart, hpoff, rowptr, bucket_base);
    hs3_kernel<<<NHS, 512, 0, stream>>>(ghist, hpoff, bucket_base);
    scatter1_kernel<<<HB, 256, 0, stream>>>(src, dst, ghist, ebuf);
    csr2_kernel<<<NBUCK, 256, 0, stream>>>(ebuf, bucket_base, rowptr, col);

    // ---- weight splits + feat hi/lo split ----
    wsplit_all_kernel<<<304, 256, 0, stream>>>(Ws1, Wn1, Ws2, Wn2, Ws3, Wn3, Wh, Wl);
    fsplit_kernel<<<(int)(NF / 4 / 256), 256, 0, stream>>>(feat, xh, xl);

    // ---- layer 1 ----
    gemm12_fused<<<GEMM_GRID, 256, 0, stream>>>(xh, xl, rowptr, col,
                                                Wsh1, Wsl1, Wnh1, Wnl1, xbuf, partials, stats);
    bnred_kernel<<<64, 256, 0, stream>>>(partials, stats, GEMM_GRID);
    bn_apply_kernel<<<(NODES * 32) / 256, 256, 0, stream>>>(xbuf, xh, xl, stats, gamma1, beta1);

    // ---- layer 2 ----
    gemm12_fused<<<GEMM_GRID, 256, 0, stream>>>(xh, xl, rowptr, col,
                                                Wsh2, Wsl2, Wnh2, Wnl2, xbuf, partials, stats);
    bnred_kernel<<<64, 256, 0, stream>>>(partials, stats, GEMM_GRID);
    bn_apply_kernel<<<(NODES * 32) / 256, 256, 0, stream>>>(xbuf, xh, xl, stats, gamma2, beta2);

    // ---- layer 3 (+fused log-softmax) ----
    gemm3_fused<<<GEMM3_GRID, 256, 0, stream>>>(xh, xl, rowptr, col,
                                                Wsh3, Wsl3, Wnh3, Wnl3, out);
}

// Round 7
// 601.453 us; speedup vs baseline: 1.3216x; 1.3216x over previous
//
#include <hip/hip_runtime.h>
#include <math.h>

#define NODES 100000
#define EDGES 1600000
#define DH 128
#define DOUT 40

// ---- CSR bucket-sort geometry ----
#define BSHIFT 9
#define NBUCK 196                 // ceil(NODES/512)
#define HB 200                    // histogram blocks
#define EPB 8000                  // edges per histogram block
#define GH (NBUCK * HB)           // 39200
#define NHS ((GH + 511) / 512)    // 77

typedef __attribute__((ext_vector_type(8))) short bf16x8;
typedef __attribute__((ext_vector_type(4))) float f32x4;

__device__ inline ushort bfh(float f) {           // f32 -> bf16 bits (RNE)
    uint u = __float_as_uint(f);
    return (ushort)((u + 0x7FFFu + ((u >> 16) & 1u)) >> 16);
}
__device__ inline float bff(ushort h) { return __uint_as_float(((uint)h) << 16); }

// ================= CSR build: no global atomics =================

__global__ __launch_bounds__(256) void hist1_kernel(const int* __restrict__ dst,
                                                    uint* __restrict__ ghist) {
    __shared__ uint h[NBUCK];
    int t = threadIdx.x;
    if (t < NBUCK) h[t] = 0;
    __syncthreads();
    int e0 = blockIdx.x * EPB;
    for (int e = e0 + t; e < e0 + EPB; e += 256)
        atomicAdd(&h[((uint)dst[e]) >> BSHIFT], 1u);
    __syncthreads();
    if (t < NBUCK) ghist[t * HB + blockIdx.x] = h[t];   // bucket-major
}

__global__ __launch_bounds__(512) void hs1_kernel(const uint* __restrict__ ghist,
                                                  uint* __restrict__ hpart) {
    __shared__ uint buf[512];
    int i = blockIdx.x * 512 + threadIdx.x;
    buf[threadIdx.x] = (i < GH) ? ghist[i] : 0;
    __syncthreads();
    for (int off = 256; off; off >>= 1) {
        if (threadIdx.x < off) buf[threadIdx.x] += buf[threadIdx.x + off];
        __syncthreads();
    }
    if (threadIdx.x == 0) hpart[blockIdx.x] = buf[0];
}

__global__ __launch_bounds__(128) void hs2_kernel(const uint* __restrict__ hpart,
                                                  uint* __restrict__ hpoff,
                                                  int* __restrict__ rowptr,
                                                  int* __restrict__ bucket_base) {
    __shared__ uint buf[128];
    uint v = (threadIdx.x < NHS) ? hpart[threadIdx.x] : 0;
    buf[threadIdx.x] = v;
    __syncthreads();
    for (int off = 1; off < 128; off <<= 1) {
        uint tv = (threadIdx.x >= off) ? buf[threadIdx.x - off] : 0;
        __syncthreads();
        buf[threadIdx.x] += tv;
        __syncthreads();
    }
    if (threadIdx.x < NHS) hpoff[threadIdx.x] = buf[threadIdx.x] - v;   // exclusive
    if (threadIdx.x == 0) { rowptr[NODES] = EDGES; bucket_base[NBUCK] = EDGES; }
}

__global__ __launch_bounds__(512) void hs3_kernel(uint* __restrict__ ghist,
                                                  const uint* __restrict__ hpoff,
                                                  int* __restrict__ bucket_base) {
    __shared__ uint buf[512];
    int i = blockIdx.x * 512 + threadIdx.x;
    uint v = (i < GH) ? ghist[i] : 0;
    buf[threadIdx.x] = v;
    __syncthreads();
    for (int off = 1; off < 512; off <<= 1) {
        uint tv = (threadIdx.x >= off) ? buf[threadIdx.x - off] : 0;
        __syncthreads();
        buf[threadIdx.x] += tv;
        __syncthreads();
    }
    if (i < GH) {
        uint ex = hpoff[blockIdx.x] + buf[threadIdx.x] - v;
        ghist[i] = ex;
        if (i % HB == 0) bucket_base[i / HB] = (int)ex;
    }
}

__global__ __launch_bounds__(256) void scatter1_kernel(const int* __restrict__ src,
                                                       const int* __restrict__ dst,
                                                       const uint* __restrict__ ghist,
                                                       uint2* __restrict__ ebuf) {
    __shared__ uint cur[NBUCK];
    int t = threadIdx.x;
    if (t < NBUCK) cur[t] = ghist[t * HB + blockIdx.x];
    __syncthreads();
    int e0 = blockIdx.x * EPB;
    for (int e = e0 + t; e < e0 + EPB; e += 256) {
        uint d = (uint)dst[e];
        uint s = (uint)src[e];
        uint pos = atomicAdd(&cur[d >> BSHIFT], 1u);
        ebuf[pos] = make_uint2(d, s);
    }
}

__global__ __launch_bounds__(256) void csr2_kernel(const uint2* __restrict__ ebuf,
                                                   const int* __restrict__ bucket_base,
                                                   int* __restrict__ rowptr,
                                                   int* __restrict__ col) {
    __shared__ uint h[512];
    __shared__ uint cur[512];
    __shared__ uint buf[256];
    int b = blockIdx.x;
    int t = threadIdx.x;
    int seg0 = bucket_base[b];
    int seg1 = bucket_base[b + 1];
    h[t] = 0; h[t + 256] = 0;
    __syncthreads();
    uint nbase = (uint)b << BSHIFT;
    for (int e = seg0 + t; e < seg1; e += 256)
        atomicAdd(&h[ebuf[e].x - nbase], 1u);
    __syncthreads();
    uint s0 = h[2 * t], s1 = h[2 * t + 1];
    uint pair = s0 + s1;
    buf[t] = pair;
    __syncthreads();
    for (int off = 1; off < 256; off <<= 1) {
        uint tv = (t >= off) ? buf[t - off] : 0;
        __syncthreads();
        buf[t] += tv;
        __syncthreads();
    }
    uint epre = buf[t] - pair;
    cur[2 * t]     = seg0 + epre;
    cur[2 * t + 1] = seg0 + epre + s0;
    int node0 = (int)nbase + 2 * t;
    if (node0 < NODES)     rowptr[node0]     = seg0 + epre;
    if (node0 + 1 < NODES) rowptr[node0 + 1] = seg0 + epre + s0;
    __syncthreads();
    for (int e = seg0 + t; e < seg1; e += 256) {
        uint2 p = ebuf[e];
        uint pos = atomicAdd(&cur[p.x - nbase], 1u);
        col[pos] = (int)p.y;
    }
}

// ================= combined weight split =================
__global__ void wsplit_all_kernel(const float* __restrict__ Ws1, const float* __restrict__ Wn1,
                                  const float* __restrict__ Ws2, const float* __restrict__ Wn2,
                                  const float* __restrict__ Ws3, const float* __restrict__ Wn3,
                                  ushort* __restrict__ Wh, ushort* __restrict__ Wl) {
    int i = blockIdx.x * blockDim.x + threadIdx.x;   // 0 .. 77823
    if (i >= 4 * 16384 + 2 * 6144) return;
    float v;
    if (i < 65536) {
        int which = i >> 14, j = i & 16383;
        const float* W = (which == 0) ? Ws1 : (which == 1) ? Wn1 : (which == 2) ? Ws2 : Wn2;
        v = W[j];
    } else {
        int i2 = i - 65536;
        int which = (i2 >= 6144) ? 1 : 0;
        int j = i2 - which * 6144;
        int n = j >> 7, k = j & 127;
        const float* W = which ? Wn3 : Ws3;
        v = (n < DOUT) ? W[n * 128 + k] : 0.f;
    }
    ushort h = bfh(v);
    Wh[i] = h;
    Wl[i] = bfh(v - bff(h));
}

// feat f32 -> hi/lo bf16 pair
__global__ void fsplit_kernel(const float* __restrict__ f, ushort* __restrict__ xh,
                              ushort* __restrict__ xl) {
    int i = blockIdx.x * blockDim.x + threadIdx.x;   // per float4
    float4 v = *reinterpret_cast<const float4*>(f + (size_t)i * 4);
    ushort4 h, l;
    h.x = bfh(v.x); h.y = bfh(v.y); h.z = bfh(v.z); h.w = bfh(v.w);
    l.x = bfh(v.x - bff(h.x)); l.y = bfh(v.y - bff(h.y));
    l.z = bfh(v.z - bff(h.z)); l.w = bfh(v.w - bff(h.w));
    *reinterpret_cast<ushort4*>(xh + (size_t)i * 4) = h;
    *reinterpret_cast<ushort4*>(xl + (size_t)i * 4) = l;
}

// ================= standalone gather (high-occupancy, unroll-2 ILP) =================
// 1 wave per node; 16 lanes per neighbor slot; 2 independent neighbor loads in flight.
__global__ __launch_bounds__(256) void gather_agg_kernel(const ushort* __restrict__ xh,
                                                         const int* __restrict__ rowptr,
                                                         const int* __restrict__ col,
                                                         float* __restrict__ agg) {
    int node = blockIdx.x * 4 + (threadIdx.x >> 6);
    int lane = threadIdx.x & 63;
    int g = lane >> 4;        // neighbor slot 0..3
    int sub = lane & 15;      // dim chunk [sub*8, sub*8+8)
    int p0 = rowptr[node], p1 = rowptr[node + 1];
    float a0[8] = {}, a1[8] = {};
    int p = p0 + g;
    for (; p + 4 < p1; p += 8) {
        int s0 = col[p];
        int s1 = col[p + 4];
        uint4 v0 = *reinterpret_cast<const uint4*>(xh + (size_t)s0 * 128 + sub * 8);
        uint4 v1 = *reinterpret_cast<const uint4*>(xh + (size_t)s1 * 128 + sub * 8);
        a0[0] += __uint_as_float(v0.x << 16); a0[1] += __uint_as_float(v0.x & 0xffff0000u);
        a0[2] += __uint_as_float(v0.y << 16); a0[3] += __uint_as_float(v0.y & 0xffff0000u);
        a0[4] += __uint_as_float(v0.z << 16); a0[5] += __uint_as_float(v0.z & 0xffff0000u);
        a0[6] += __uint_as_float(v0.w << 16); a0[7] += __uint_as_float(v0.w & 0xffff0000u);
        a1[0] += __uint_as_float(v1.x << 16); a1[1] += __uint_as_float(v1.x & 0xffff0000u);
        a1[2] += __uint_as_float(v1.y << 16); a1[3] += __uint_as_float(v1.y & 0xffff0000u);
        a1[4] += __uint_as_float(v1.z << 16); a1[5] += __uint_as_float(v1.z & 0xffff0000u);
        a1[6] += __uint_as_float(v1.w << 16); a1[7] += __uint_as_float(v1.w & 0xffff0000u);
    }
    if (p < p1) {
        int s = col[p];
        uint4 v = *reinterpret_cast<const uint4*>(xh + (size_t)s * 128 + sub * 8);
        a0[0] += __uint_as_float(v.x << 16); a0[1] += __uint_as_float(v.x & 0xffff0000u);
        a0[2] += __uint_as_float(v.y << 16); a0[3] += __uint_as_float(v.y & 0xffff0000u);
        a0[4] += __uint_as_float(v.z << 16); a0[5] += __uint_as_float(v.z & 0xffff0000u);
        a0[6] += __uint_as_float(v.w << 16); a0[7] += __uint_as_float(v.w & 0xffff0000u);
    }
#pragma unroll
    for (int j = 0; j < 8; ++j) {
        a0[j] += a1[j];
        a0[j] += __shfl_xor(a0[j], 16, 64);
        a0[j] += __shfl_xor(a0[j], 32, 64);
    }
    if (lane < 16) {
        float rd = 1.0f / fmaxf((float)(p1 - p0), 1.0f);
        float4 o0 = make_float4(a0[0] * rd, a0[1] * rd, a0[2] * rd, a0[3] * rd);
        float4 o1 = make_float4(a0[4] * rd, a0[5] * rd, a0[6] * rd, a0[7] * rd);
        *reinterpret_cast<float4*>(agg + (size_t)node * 128 + sub * 8) = o0;
        *reinterpret_cast<float4*>(agg + (size_t)node * 128 + sub * 8 + 4) = o1;
    }
}

// ================= MFMA GEMMs (3x-bf16 split) =================

__device__ inline void split4(float4 v, ushort4& h, ushort4& l) {
    h.x = bfh(v.x); h.y = bfh(v.y); h.z = bfh(v.z); h.w = bfh(v.w);
    l.x = bfh(v.x - bff(h.x)); l.y = bfh(v.y - bff(h.y));
    l.z = bfh(v.z - bff(h.z)); l.w = bfh(v.w - bff(h.w));
}

#define MFMA(a, b, c) __builtin_amdgcn_mfma_f32_16x16x32_bf16(a, b, c, 0, 0, 0)

// layers 1,2: reads xh/xl (pure copy) + agg f32 (split in staging);
// writes pre-BN packed hi|lo uint IN-PLACE into agg (block-local rows, read-before-write);
// emits per-block BN column partials; block 0 zeroes stats for bnred.
__global__ __launch_bounds__(256) void gemm12_kernel(
    const ushort* __restrict__ xh, const ushort* __restrict__ xl,
    float* agg,   // in: f32 neighbor means; out (aliased): packed hi|lo pre-BN
    const ushort* __restrict__ Wsh, const ushort* __restrict__ Wsl,
    const ushort* __restrict__ Wnh, const ushort* __restrict__ Wnl,
    float* __restrict__ partials, float* __restrict__ stat0) {
    if (blockIdx.x == 0) stat0[threadIdx.x] = 0.f;   // zero stats[256] for bnred
    __shared__ ushort xh_s[32 * 128], xl_s[32 * 128], ah_s[32 * 128], al_s[32 * 128];
    int t = threadIdx.x;
    int row0 = blockIdx.x * 32;
    // stage self rows: pure copy of pre-split hi/lo
#pragma unroll
    for (int i = 0; i < 2; ++i) {
        int f = t + i * 256;            // 512 chunks of 8 shorts
        int r = f >> 4;
        int c0 = (f & 15) * 8;
        int cs = c0 ^ ((r & 7) << 3);
        *reinterpret_cast<uint4*>(&xh_s[r * 128 + cs]) =
            *reinterpret_cast<const uint4*>(xh + (size_t)(row0 + r) * 128 + c0);
        *reinterpret_cast<uint4*>(&xl_s[r * 128 + cs]) =
            *reinterpret_cast<const uint4*>(xl + (size_t)(row0 + r) * 128 + c0);
    }
    // stage agg rows: split f32 -> hi/lo
#pragma unroll
    for (int i = 0; i < 4; ++i) {
        int c = t + i * 256;            // 1024 float4 chunks
        int r = c >> 5;
        int c0 = (c & 31) * 4;
        int cs = c0 ^ ((r & 7) << 3);
        float4 av = *reinterpret_cast<const float4*>(agg + (size_t)(row0 + r) * 128 + c0);
        ushort4 h, l;
        split4(av, h, l);
        *reinterpret_cast<ushort4*>(&ah_s[r * 128 + cs]) = h;
        *reinterpret_cast<ushort4*>(&al_s[r * 128 + cs]) = l;
    }
    __syncthreads();
    int w = t >> 6;
    int l = t & 63;
    int lr = l & 15;
    int kq = (l >> 4) * 8;
    int n0 = w * 32;
    f32x4 acc[2][2] = {};
    for (int kk = 0; kk < 4; ++kk) {
        int kf = kk * 32 + kq;
        bf16x8 a_xh[2], a_xl[2], a_ah[2], a_al[2];
#pragma unroll
        for (int rt = 0; rt < 2; ++rt) {
            int r = rt * 16 + lr;
            int ks = kf ^ ((r & 7) << 3);
            a_xh[rt] = *reinterpret_cast<const bf16x8*>(&xh_s[r * 128 + ks]);
            a_xl[rt] = *reinterpret_cast<const bf16x8*>(&xl_s[r * 128 + ks]);
            a_ah[rt] = *reinterpret_cast<const bf16x8*>(&ah_s[r * 128 + ks]);
            a_al[rt] = *reinterpret_cast<const bf16x8*>(&al_s[r * 128 + ks]);
        }
#pragma unroll
        for (int ct = 0; ct < 2; ++ct) {
            size_t wo = (size_t)(n0 + ct * 16 + lr) * 128 + kf;
            bf16x8 bsh = *reinterpret_cast<const bf16x8*>(Wsh + wo);
            bf16x8 bsl = *reinterpret_cast<const bf16x8*>(Wsl + wo);
            bf16x8 bnh = *reinterpret_cast<const bf16x8*>(Wnh + wo);
            bf16x8 bnl = *reinterpret_cast<const bf16x8*>(Wnl + wo);
#pragma unroll
            for (int rt = 0; rt < 2; ++rt) {
                acc[rt][ct] = MFMA(a_xh[rt], bsh, acc[rt][ct]);
                acc[rt][ct] = MFMA(a_xh[rt], bsl, acc[rt][ct]);
                acc[rt][ct] = MFMA(a_xl[rt], bsh, acc[rt][ct]);
                acc[rt][ct] = MFMA(a_ah[rt], bnh, acc[rt][ct]);
                acc[rt][ct] = MFMA(a_ah[rt], bnl, acc[rt][ct]);
                acc[rt][ct] = MFMA(a_al[rt], bnh, acc[rt][ct]);
            }
        }
    }
    // epilogue: pre-BN packed hi|lo in-place into agg (this block's own rows only)
    uint* pb = reinterpret_cast<uint*>(agg);
    int dr = (l >> 4) * 4;
#pragma unroll
    for (int rt = 0; rt < 2; ++rt)
#pragma unroll
        for (int ct = 0; ct < 2; ++ct)
#pragma unroll
            for (int j = 0; j < 4; ++j) {
                float v = acc[rt][ct][j];
                ushort hi = bfh(v);
                ushort lo = bfh(v - bff(hi));
                pb[(size_t)(row0 + rt * 16 + dr + j) * 128 + n0 + ct * 16 + lr] =
                    (uint)hi | ((uint)lo << 16);
            }
    // BN column partials from registers
    float s0 = 0.f, q0 = 0.f, s1 = 0.f, q1 = 0.f;
#pragma unroll
    for (int rt = 0; rt < 2; ++rt)
#pragma unroll
        for (int j = 0; j < 4; ++j) {
            float v0 = acc[rt][0][j], v1 = acc[rt][1][j];
            s0 += v0; q0 += v0 * v0;
            s1 += v1; q1 += v1 * v1;
        }
    s0 += __shfl_xor(s0, 16, 64); s0 += __shfl_xor(s0, 32, 64);
    q0 += __shfl_xor(q0, 16, 64); q0 += __shfl_xor(q0, 32, 64);
    s1 += __shfl_xor(s1, 16, 64); s1 += __shfl_xor(s1, 32, 64);
    q1 += __shfl_xor(q1, 16, 64); q1 += __shfl_xor(q1, 32, 64);
    if (l < 16) {
        float* pbp = partials + (size_t)blockIdx.x * 256;
        pbp[n0 + lr] = s0;
        pbp[n0 + 16 + lr] = s1;
        pbp[128 + n0 + lr] = q0;
        pbp[128 + n0 + 16 + lr] = q1;
    }
}

// reduce per-block partials -> stats[256]
__global__ __launch_bounds__(256) void bnred_kernel(const float* __restrict__ partials,
                                                    float* __restrict__ stats, int nblk) {
    float s = 0.f;
    for (int b = blockIdx.x; b < nblk; b += gridDim.x)
        s += partials[(size_t)b * 256 + threadIdx.x];
    atomicAdd(&stats[threadIdx.x], s);
}

// BN finalize+apply+relu: reads packed hi|lo pre-BN, writes post-BN hi/lo bf16
__global__ void bn_apply_kernel(const uint* __restrict__ pb, ushort* __restrict__ xh,
                                ushort* __restrict__ xl, const float* __restrict__ stats,
                                const float* __restrict__ gamma, const float* __restrict__ beta) {
    long long t = (long long)blockIdx.x * blockDim.x + threadIdx.x;
    if (t >= (long long)NODES * 32) return;
    int j4 = ((int)(t & 31)) * 4;
    size_t off = (size_t)(t >> 5) * 128 + j4;
    uint4 u = *reinterpret_cast<const uint4*>(pb + off);
    float4 v;
    v.x = __uint_as_float(u.x << 16) + __uint_as_float(u.x & 0xffff0000u);
    v.y = __uint_as_float(u.y << 16) + __uint_as_float(u.y & 0xffff0000u);
    v.z = __uint_as_float(u.z << 16) + __uint_as_float(u.z & 0xffff0000u);
    v.w = __uint_as_float(u.w << 16) + __uint_as_float(u.w & 0xffff0000u);
    float4 s4 = *reinterpret_cast<const float4*>(stats + j4);
    float4 q4 = *reinterpret_cast<const float4*>(stats + 128 + j4);
    float4 g4 = *reinterpret_cast<const float4*>(gamma + j4);
    float4 be4 = *reinterpret_cast<const float4*>(beta + j4);
    const float inv = 1.0f / NODES;
    float m, var, a;
    m = s4.x * inv; var = q4.x * inv - m * m; a = g4.x * rsqrtf(var + 1e-5f);
    v.x = fmaxf(v.x * a + (be4.x - m * a), 0.f);
    m = s4.y * inv; var = q4.y * inv - m * m; a = g4.y * rsqrtf(var + 1e-5f);
    v.y = fmaxf(v.y * a + (be4.y - m * a), 0.f);
    m = s4.z * inv; var = q4.z * inv - m * m; a = g4.z * rsqrtf(var + 1e-5f);
    v.z = fmaxf(v.z * a + (be4.z - m * a), 0.f);
    m = s4.w * inv; var = q4.w * inv - m * m; a = g4.w * rsqrtf(var + 1e-5f);
    v.w = fmaxf(v.w * a + (be4.w - m * a), 0.f);
    ushort4 hh, ll;
    hh.x = bfh(v.x); hh.y = bfh(v.y); hh.z = bfh(v.z); hh.w = bfh(v.w);
    ll.x = bfh(v.x - bff(hh.x)); ll.y = bfh(v.y - bff(hh.y));
    ll.z = bfh(v.z - bff(hh.z)); ll.w = bfh(v.w - bff(hh.w));
    *reinterpret_cast<ushort4*>(xh + off) = hh;
    *reinterpret_cast<ushort4*>(xl + off) = ll;
}

// ================= GEMM3 + fused log-softmax (gather NOT fused) =================
__global__ __launch_bounds__(256) void gemm3_kernel(
    const ushort* __restrict__ xh, const ushort* __restrict__ xl,
    const float* __restrict__ agg,
    const ushort* __restrict__ Wsh, const ushort* __restrict__ Wsl,
    const ushort* __restrict__ Wnh, const ushort* __restrict__ Wnl,
    float* __restrict__ out) {
    __shared__ ushort xh_s[64 * 128], xl_s[64 * 128], ah_s[64 * 128], al_s[64 * 128];
    int t = threadIdx.x;
    int row0 = blockIdx.x * 64;
#pragma unroll
    for (int i = 0; i < 4; ++i) {
        int f = t + i * 256;            // 1024 chunks of 8 shorts
        int r = f >> 4;
        int c0 = (f & 15) * 8;
        int cs = c0 ^ ((r & 7) << 3);
        int rr = row0 + r; if (rr >= NODES) rr = NODES - 1;
        *reinterpret_cast<uint4*>(&xh_s[r * 128 + cs]) =
            *reinterpret_cast<const uint4*>(xh + (size_t)rr * 128 + c0);
        *reinterpret_cast<uint4*>(&xl_s[r * 128 + cs]) =
            *reinterpret_cast<const uint4*>(xl + (size_t)rr * 128 + c0);
    }
#pragma unroll
    for (int i = 0; i < 8; ++i) {
        int c = t + i * 256;            // 2048 float4 chunks
        int r = c >> 5;
        int c0 = (c & 31) * 4;
        int cs = c0 ^ ((r & 7) << 3);
        int rr = row0 + r; if (rr >= NODES) rr = NODES - 1;
        float4 av = *reinterpret_cast<const float4*>(agg + (size_t)rr * 128 + c0);
        ushort4 h, l;
        split4(av, h, l);
        *reinterpret_cast<ushort4*>(&ah_s[r * 128 + cs]) = h;
        *reinterpret_cast<ushort4*>(&al_s[r * 128 + cs]) = l;
    }
    __syncthreads();
    int w = t >> 6;
    int l = t & 63;
    int lr = l & 15;
    int kq = (l >> 4) * 8;
    f32x4 acc[3] = {};
    for (int kk = 0; kk < 4; ++kk) {
        int kf = kk * 32 + kq;
        int r = w * 16 + lr;
        int ks = kf ^ ((r & 7) << 3);
        bf16x8 a_xh = *reinterpret_cast<const bf16x8*>(&xh_s[r * 128 + ks]);
        bf16x8 a_xl = *reinterpret_cast<const bf16x8*>(&xl_s[r * 128 + ks]);
        bf16x8 a_ah = *reinterpret_cast<const bf16x8*>(&ah_s[r * 128 + ks]);
        bf16x8 a_al = *reinterpret_cast<const bf16x8*>(&al_s[r * 128 + ks]);
#pragma unroll
        for (int ct = 0; ct < 3; ++ct) {
            size_t wo = (size_t)(ct * 16 + lr) * 128 + kf;
            bf16x8 bsh = *reinterpret_cast<const bf16x8*>(Wsh + wo);
            bf16x8 bsl = *reinterpret_cast<const bf16x8*>(Wsl + wo);
            bf16x8 bnh = *reinterpret_cast<const bf16x8*>(Wnh + wo);
            bf16x8 bnl = *reinterpret_cast<const bf16x8*>(Wnl + wo);
            acc[ct] = MFMA(a_xh, bsh, acc[ct]);
            acc[ct] = MFMA(a_xh, bsl, acc[ct]);
            acc[ct] = MFMA(a_xl, bsh, acc[ct]);
            acc[ct] = MFMA(a_ah, bnh, acc[ct]);
            acc[ct] = MFMA(a_ah, bnl, acc[ct]);
            acc[ct] = MFMA(a_al, bnh, acc[ct]);
        }
    }
    int dr = (l >> 4) * 4;
#pragma unroll
    for (int j = 0; j < 4; ++j) {
        float v0 = acc[0][j], v1 = acc[1][j];
        float v2 = (lr < 8) ? acc[2][j] : -INFINITY;
        float m = fmaxf(v0, fmaxf(v1, v2));
#pragma unroll
        for (int o = 8; o; o >>= 1) m = fmaxf(m, __shfl_xor(m, o, 16));
        float e = expf(v0 - m) + expf(v1 - m) + ((lr < 8) ? expf(v2 - m) : 0.f);
#pragma unroll
        for (int o = 8; o; o >>= 1) e += __shfl_xor(e, o, 16);
        float lse = m + logf(e);
        int row = row0 + w * 16 + dr + j;
        if (row < NODES) {
            out[(size_t)row * DOUT + lr] = v0 - lse;
            out[(size_t)row * DOUT + 16 + lr] = v1 - lse;
            if (lr < 8) out[(size_t)row * DOUT + 32 + lr] = acc[2][j] - lse;
        }
    }
}

extern "C" void kernel_launch(void* const* d_in, const int* in_sizes, int n_in,
                              void* d_out, int out_size, void* d_ws, size_t ws_size,
                              hipStream_t stream) {
    const float* feat   = (const float*)d_in[0];
    const float* Ws1    = (const float*)d_in[1];
    const float* Wn1    = (const float*)d_in[2];
    const float* gamma1 = (const float*)d_in[3];
    const float* beta1  = (const float*)d_in[4];
    const float* Ws2    = (const float*)d_in[5];
    const float* Wn2    = (const float*)d_in[6];
    const float* gamma2 = (const float*)d_in[7];
    const float* beta2  = (const float*)d_in[8];
    const float* Ws3    = (const float*)d_in[9];
    const float* Wn3    = (const float*)d_in[10];
    const int*   src    = (const int*)d_in[11];
    const int*   dst    = (const int*)d_in[12];
    float* out = (float*)d_out;

    float* ws = (float*)d_ws;
    const size_t NF = (size_t)NODES * 128;
    float* agg  = ws;                       // N*128 f32; aliases: ebuf (CSR phase), packed pre-BN (post-GEMM)
    float* stats = ws + NF;                 // 256 f32
    float* partials = stats + 256;          // 3125*256 f32
    ushort* xh = (ushort*)(partials + 3125 * 256);   // N*128 bf16 hi
    ushort* xl = xh + NF;                   // N*128 bf16 lo
    ushort* Wh = xl + NF;                   // 77824
    ushort* Wl = Wh + 77824;
    int* rowptr = (int*)(Wl + 77824);       // N+1
    uint* ghist = (uint*)(rowptr + NODES + 1);
    uint* hpart = ghist + GH;               // 128
    uint* hpoff = hpart + 128;              // 128
    int* bucket_base = (int*)(hpoff + 128); // NBUCK+1
    int* col    = bucket_base + NBUCK + 1;  // E
    uint2* ebuf = (uint2*)agg;              // E uint2 = 12.8MB, dead before gather L1

    ushort* Wsh1 = Wh;           ushort* Wsl1 = Wl;
    ushort* Wnh1 = Wh + 16384;   ushort* Wnl1 = Wl + 16384;
    ushort* Wsh2 = Wh + 32768;   ushort* Wsl2 = Wl + 32768;
    ushort* Wnh2 = Wh + 49152;   ushort* Wnl2 = Wl + 49152;
    ushort* Wsh3 = Wh + 65536;   ushort* Wsl3 = Wl + 65536;
    ushort* Wnh3 = Wh + 71680;   ushort* Wnl3 = Wl + 71680;

    const int GEMM_GRID  = NODES / 32;           // 3125
    const int GEMM3_GRID = (NODES + 63) / 64;    // 1563
    const int AGG_GRID   = NODES / 4;            // 25000

    // ---- CSR build: bucket sort, LDS atomics only ----
    hist1_kernel<<<HB, 256, 0, stream>>>(dst, ghist);
    hs1_kernel<<<NHS, 512, 0, stream>>>(ghist, hpart);
    hs2_kernel<<<1, 128, 0, stream>>>(hpart, hpoff, rowptr, bucket_base);
    hs3_kernel<<<NHS, 512, 0, stream>>>(ghist, hpoff, bucket_base);
    scatter1_kernel<<<HB, 256, 0, stream>>>(src, dst, ghist, ebuf);
    csr2_kernel<<<NBUCK, 256, 0, stream>>>(ebuf, bucket_base, rowptr, col);

    // ---- weight splits + feat hi/lo split ----
    wsplit_all_kernel<<<304, 256, 0, stream>>>(Ws1, Wn1, Ws2, Wn2, Ws3, Wn3, Wh, Wl);
    fsplit_kernel<<<(int)(NF / 4 / 256), 256, 0, stream>>>(feat, xh, xl);

    // ---- layer 1 ----
    gather_agg_kernel<<<AGG_GRID, 256, 0, stream>>>(xh, rowptr, col, agg);
    gemm12_kernel<<<GEMM_GRID, 256, 0, stream>>>(xh, xl, agg,
                                                 Wsh1, Wsl1, Wnh1, Wnl1, partials, stats);
    bnred_kernel<<<64, 256, 0, stream>>>(partials, stats, GEMM_GRID);
    bn_apply_kernel<<<(NODES * 32) / 256, 256, 0, stream>>>((uint*)agg, xh, xl, stats, gamma1, beta1);

    // ---- layer 2 ----
    gather_agg_kernel<<<AGG_GRID, 256, 0, stream>>>(xh, rowptr, col, agg);
    gemm12_kernel<<<GEMM_GRID, 256, 0, stream>>>(xh, xl, agg,
                                                 Wsh2, Wsl2, Wnh2, Wnl2, partials, stats);
    bnred_kernel<<<64, 256, 0, stream>>>(partials, stats, GEMM_GRID);
    bn_apply_kernel<<<(NODES * 32) / 256, 256, 0, stream>>>((uint*)agg, xh, xl, stats, gamma2, beta2);

    // ---- layer 3 (+fused log-softmax) ----
    gather_agg_kernel<<<AGG_GRID, 256, 0, stream>>>(xh, rowptr, col, agg);
    gemm3_kernel<<<GEMM3_GRID, 256, 0, stream>>>(xh, xl, agg,
                                                 Wsh3, Wsl3, Wnh3, Wnl3, out);
}

// Round 9
// 580.156 us; speedup vs baseline: 1.3701x; 1.0367x over previous
//
#include <hip/hip_runtime.h>
#include <math.h>

#define NODES 100000
#define EDGES 1600000
#define DH 128
#define DOUT 40

// ---- CSR bucket-sort geometry ----
#define BSHIFT 9
#define NBUCK 196                 // ceil(NODES/512)
#define HB 200                    // histogram blocks
#define EPB 8000                  // edges per histogram block
#define GH (NBUCK * HB)           // 39200
#define NHS ((GH + 511) / 512)    // 77

typedef __attribute__((ext_vector_type(8))) short bf16x8;
typedef __attribute__((ext_vector_type(4))) float f32x4;

__device__ inline ushort bfh(float f) {           // f32 -> bf16 bits (RNE)
    uint u = __float_as_uint(f);
    return (ushort)((u + 0x7FFFu + ((u >> 16) & 1u)) >> 16);
}
__device__ inline float bff(ushort h) { return __uint_as_float(((uint)h) << 16); }

// ================= CSR build: no global atomics =================

__global__ __launch_bounds__(256) void hist1_kernel(const int* __restrict__ dst,
                                                    uint* __restrict__ ghist) {
    __shared__ uint h[NBUCK];
    int t = threadIdx.x;
    if (t < NBUCK) h[t] = 0;
    __syncthreads();
    int e0 = blockIdx.x * EPB;
    for (int e = e0 + t; e < e0 + EPB; e += 256)
        atomicAdd(&h[((uint)dst[e]) >> BSHIFT], 1u);
    __syncthreads();
    if (t < NBUCK) ghist[t * HB + blockIdx.x] = h[t];   // bucket-major
}

__global__ __launch_bounds__(512) void hs1_kernel(const uint* __restrict__ ghist,
                                                  uint* __restrict__ hpart) {
    __shared__ uint buf[512];
    int i = blockIdx.x * 512 + threadIdx.x;
    buf[threadIdx.x] = (i < GH) ? ghist[i] : 0;
    __syncthreads();
    for (int off = 256; off; off >>= 1) {
        if (threadIdx.x < off) buf[threadIdx.x] += buf[threadIdx.x + off];
        __syncthreads();
    }
    if (threadIdx.x == 0) hpart[blockIdx.x] = buf[0];
}

__global__ __launch_bounds__(128) void hs2_kernel(const uint* __restrict__ hpart,
                                                  uint* __restrict__ hpoff,
                                                  int* __restrict__ rowptr,
                                                  int* __restrict__ bucket_base) {
    __shared__ uint buf[128];
    uint v = (threadIdx.x < NHS) ? hpart[threadIdx.x] : 0;
    buf[threadIdx.x] = v;
    __syncthreads();
    for (int off = 1; off < 128; off <<= 1) {
        uint tv = (threadIdx.x >= off) ? buf[threadIdx.x - off] : 0;
        __syncthreads();
        buf[threadIdx.x] += tv;
        __syncthreads();
    }
    if (threadIdx.x < NHS) hpoff[threadIdx.x] = buf[threadIdx.x] - v;   // exclusive
    if (threadIdx.x == 0) { rowptr[NODES] = EDGES; bucket_base[NBUCK] = EDGES; }
}

__global__ __launch_bounds__(512) void hs3_kernel(uint* __restrict__ ghist,
                                                  const uint* __restrict__ hpoff,
                                                  int* __restrict__ bucket_base) {
    __shared__ uint buf[512];
    int i = blockIdx.x * 512 + threadIdx.x;
    uint v = (i < GH) ? ghist[i] : 0;
    buf[threadIdx.x] = v;
    __syncthreads();
    for (int off = 1; off < 512; off <<= 1) {
        uint tv = (threadIdx.x >= off) ? buf[threadIdx.x - off] : 0;
        __syncthreads();
        buf[threadIdx.x] += tv;
        __syncthreads();
    }
    if (i < GH) {
        uint ex = hpoff[blockIdx.x] + buf[threadIdx.x] - v;
        ghist[i] = ex;
        if (i % HB == 0) bucket_base[i / HB] = (int)ex;
    }
}

__global__ __launch_bounds__(256) void scatter1_kernel(const int* __restrict__ src,
                                                       const int* __restrict__ dst,
                                                       const uint* __restrict__ ghist,
                                                       uint2* __restrict__ ebuf) {
    __shared__ uint cur[NBUCK];
    int t = threadIdx.x;
    if (t < NBUCK) cur[t] = ghist[t * HB + blockIdx.x];
    __syncthreads();
    int e0 = blockIdx.x * EPB;
    for (int e = e0 + t; e < e0 + EPB; e += 256) {
        uint d = (uint)dst[e];
        uint s = (uint)src[e];
        uint pos = atomicAdd(&cur[d >> BSHIFT], 1u);
        ebuf[pos] = make_uint2(d, s);
    }
}

__global__ __launch_bounds__(256) void csr2_kernel(const uint2* __restrict__ ebuf,
                                                   const int* __restrict__ bucket_base,
                                                   int* __restrict__ rowptr,
                                                   int* __restrict__ col) {
    __shared__ uint h[512];
    __shared__ uint cur[512];
    __shared__ uint buf[256];
    int b = blockIdx.x;
    int t = threadIdx.x;
    int seg0 = bucket_base[b];
    int seg1 = bucket_base[b + 1];
    h[t] = 0; h[t + 256] = 0;
    __syncthreads();
    uint nbase = (uint)b << BSHIFT;
    for (int e = seg0 + t; e < seg1; e += 256)
        atomicAdd(&h[ebuf[e].x - nbase], 1u);
    __syncthreads();
    uint s0 = h[2 * t], s1 = h[2 * t + 1];
    uint pair = s0 + s1;
    buf[t] = pair;
    __syncthreads();
    for (int off = 1; off < 256; off <<= 1) {
        uint tv = (t >= off) ? buf[t - off] : 0;
        __syncthreads();
        buf[t] += tv;
        __syncthreads();
    }
    uint epre = buf[t] - pair;
    cur[2 * t]     = seg0 + epre;
    cur[2 * t + 1] = seg0 + epre + s0;
    int node0 = (int)nbase + 2 * t;
    if (node0 < NODES)     rowptr[node0]     = seg0 + epre;
    if (node0 + 1 < NODES) rowptr[node0 + 1] = seg0 + epre + s0;
    __syncthreads();
    for (int e = seg0 + t; e < seg1; e += 256) {
        uint2 p = ebuf[e];
        uint pos = atomicAdd(&cur[p.x - nbase], 1u);
        col[pos] = (int)p.y;
    }
}

// ================= combined weight split =================
__global__ void wsplit_all_kernel(const float* __restrict__ Ws1, const float* __restrict__ Wn1,
                                  const float* __restrict__ Ws2, const float* __restrict__ Wn2,
                                  const float* __restrict__ Ws3, const float* __restrict__ Wn3,
                                  ushort* __restrict__ Wh, ushort* __restrict__ Wl) {
    int i = blockIdx.x * blockDim.x + threadIdx.x;   // 0 .. 77823
    if (i >= 4 * 16384 + 2 * 6144) return;
    float v;
    if (i < 65536) {
        int which = i >> 14, j = i & 16383;
        const float* W = (which == 0) ? Ws1 : (which == 1) ? Wn1 : (which == 2) ? Ws2 : Wn2;
        v = W[j];
    } else {
        int i2 = i - 65536;
        int which = (i2 >= 6144) ? 1 : 0;
        int j = i2 - which * 6144;
        int n = j >> 7, k = j & 127;
        const float* W = which ? Wn3 : Ws3;
        v = (n < DOUT) ? W[n * 128 + k] : 0.f;
    }
    ushort h = bfh(v);
    Wh[i] = h;
    Wl[i] = bfh(v - bff(h));
}

// feat f32 -> hi/lo bf16 pair
__global__ void fsplit_kernel(const float* __restrict__ f, ushort* __restrict__ xh,
                              ushort* __restrict__ xl) {
    int i = blockIdx.x * blockDim.x + threadIdx.x;   // per float4
    float4 v = *reinterpret_cast<const float4*>(f + (size_t)i * 4);
    ushort4 h, l;
    h.x = bfh(v.x); h.y = bfh(v.y); h.z = bfh(v.z); h.w = bfh(v.w);
    l.x = bfh(v.x - bff(h.x)); l.y = bfh(v.y - bff(h.y));
    l.z = bfh(v.z - bff(h.z)); l.w = bfh(v.w - bff(h.w));
    *reinterpret_cast<ushort4*>(xh + (size_t)i * 4) = h;
    *reinterpret_cast<ushort4*>(xl + (size_t)i * 4) = l;
}

// ================= standalone gather: writes neighbor mean as bf16 =================
__global__ __launch_bounds__(256) void gather_agg_kernel(const ushort* __restrict__ xh,
                                                         const int* __restrict__ rowptr,
                                                         const int* __restrict__ col,
                                                         ushort* __restrict__ ahb) {
    int node = blockIdx.x * 4 + (threadIdx.x >> 6);
    int lane = threadIdx.x & 63;
    int g = lane >> 4;        // neighbor slot 0..3
    int sub = lane & 15;      // dim chunk [sub*8, sub*8+8)
    int p0 = rowptr[node], p1 = rowptr[node + 1];
    float a0[8] = {}, a1[8] = {};
    int p = p0 + g;
    for (; p + 4 < p1; p += 8) {
        int s0 = col[p];
        int s1 = col[p + 4];
        uint4 v0 = *reinterpret_cast<const uint4*>(xh + (size_t)s0 * 128 + sub * 8);
        uint4 v1 = *reinterpret_cast<const uint4*>(xh + (size_t)s1 * 128 + sub * 8);
        a0[0] += __uint_as_float(v0.x << 16); a0[1] += __uint_as_float(v0.x & 0xffff0000u);
        a0[2] += __uint_as_float(v0.y << 16); a0[3] += __uint_as_float(v0.y & 0xffff0000u);
        a0[4] += __uint_as_float(v0.z << 16); a0[5] += __uint_as_float(v0.z & 0xffff0000u);
        a0[6] += __uint_as_float(v0.w << 16); a0[7] += __uint_as_float(v0.w & 0xffff0000u);
        a1[0] += __uint_as_float(v1.x << 16); a1[1] += __uint_as_float(v1.x & 0xffff0000u);
        a1[2] += __uint_as_float(v1.y << 16); a1[3] += __uint_as_float(v1.y & 0xffff0000u);
        a1[4] += __uint_as_float(v1.z << 16); a1[5] += __uint_as_float(v1.z & 0xffff0000u);
        a1[6] += __uint_as_float(v1.w << 16); a1[7] += __uint_as_float(v1.w & 0xffff0000u);
    }
    if (p < p1) {
        int s = col[p];
        uint4 v = *reinterpret_cast<const uint4*>(xh + (size_t)s * 128 + sub * 8);
        a0[0] += __uint_as_float(v.x << 16); a0[1] += __uint_as_float(v.x & 0xffff0000u);
        a0[2] += __uint_as_float(v.y << 16); a0[3] += __uint_as_float(v.y & 0xffff0000u);
        a0[4] += __uint_as_float(v.z << 16); a0[5] += __uint_as_float(v.z & 0xffff0000u);
        a0[6] += __uint_as_float(v.w << 16); a0[7] += __uint_as_float(v.w & 0xffff0000u);
    }
#pragma unroll
    for (int j = 0; j < 8; ++j) {
        a0[j] += a1[j];
        a0[j] += __shfl_xor(a0[j], 16, 64);
        a0[j] += __shfl_xor(a0[j], 32, 64);
    }
    if (lane < 16) {
        float rd = 1.0f / fmaxf((float)(p1 - p0), 1.0f);
        uint4 o;
        o.x = (uint)bfh(a0[0] * rd) | ((uint)bfh(a0[1] * rd) << 16);
        o.y = (uint)bfh(a0[2] * rd) | ((uint)bfh(a0[3] * rd) << 16);
        o.z = (uint)bfh(a0[4] * rd) | ((uint)bfh(a0[5] * rd) << 16);
        o.w = (uint)bfh(a0[6] * rd) | ((uint)bfh(a0[7] * rd) << 16);
        *reinterpret_cast<uint4*>(ahb + (size_t)node * 128 + sub * 8) = o;
    }
}

// ================= MFMA GEMMs (5-MFMA: self hh+hl+lh, neigh hh+hl) =================

#define MFMA(a, b, c) __builtin_amdgcn_mfma_f32_16x16x32_bf16(a, b, c, 0, 0, 0)

__global__ __launch_bounds__(256) void gemm12_kernel(
    const ushort* __restrict__ xh, const ushort* __restrict__ xl,
    const ushort* __restrict__ ahb, uint* __restrict__ pbuf,
    const ushort* __restrict__ Wsh, const ushort* __restrict__ Wsl,
    const ushort* __restrict__ Wnh, const ushort* __restrict__ Wnl,
    float* __restrict__ partials, float* __restrict__ stat0) {
    if (blockIdx.x == 0) stat0[threadIdx.x] = 0.f;   // zero stats[256] for bnred
    __shared__ ushort xh_s[32 * 128], xl_s[32 * 128], ah_s[32 * 128];
    int t = threadIdx.x;
    int row0 = blockIdx.x * 32;
    // stage: pure 16B copies with XOR swizzle
#pragma unroll
    for (int i = 0; i < 2; ++i) {
        int f = t + i * 256;            // 512 chunks of 8 shorts
        int r = f >> 4;
        int c0 = (f & 15) * 8;
        int cs = c0 ^ ((r & 7) << 3);
        size_t go = (size_t)(row0 + r) * 128 + c0;
        *reinterpret_cast<uint4*>(&xh_s[r * 128 + cs]) = *reinterpret_cast<const uint4*>(xh + go);
        *reinterpret_cast<uint4*>(&xl_s[r * 128 + cs]) = *reinterpret_cast<const uint4*>(xl + go);
        *reinterpret_cast<uint4*>(&ah_s[r * 128 + cs]) = *reinterpret_cast<const uint4*>(ahb + go);
    }
    __syncthreads();
    int w = t >> 6;
    int l = t & 63;
    int lr = l & 15;
    int kq = (l >> 4) * 8;
    int n0 = w * 32;
    f32x4 acc[2][2] = {};
#pragma unroll
    for (int kk = 0; kk < 4; ++kk) {
        int kf = kk * 32 + kq;
        bf16x8 a_xh[2], a_xl[2], a_ah[2];
#pragma unroll
        for (int rt = 0; rt < 2; ++rt) {
            int r = rt * 16 + lr;
            int ks = kf ^ ((r & 7) << 3);
            a_xh[rt] = *reinterpret_cast<const bf16x8*>(&xh_s[r * 128 + ks]);
            a_xl[rt] = *reinterpret_cast<const bf16x8*>(&xl_s[r * 128 + ks]);
            a_ah[rt] = *reinterpret_cast<const bf16x8*>(&ah_s[r * 128 + ks]);
        }
#pragma unroll
        for (int ct = 0; ct < 2; ++ct) {
            size_t wo = (size_t)(n0 + ct * 16 + lr) * 128 + kf;
            bf16x8 bsh = *reinterpret_cast<const bf16x8*>(Wsh + wo);
            bf16x8 bsl = *reinterpret_cast<const bf16x8*>(Wsl + wo);
            bf16x8 bnh = *reinterpret_cast<const bf16x8*>(Wnh + wo);
            bf16x8 bnl = *reinterpret_cast<const bf16x8*>(Wnl + wo);
#pragma unroll
            for (int rt = 0; rt < 2; ++rt) {
                acc[rt][ct] = MFMA(a_xh[rt], bsh, acc[rt][ct]);
                acc[rt][ct] = MFMA(a_xh[rt], bsl, acc[rt][ct]);
                acc[rt][ct] = MFMA(a_xl[rt], bsh, acc[rt][ct]);
                acc[rt][ct] = MFMA(a_ah[rt], bnh, acc[rt][ct]);
                acc[rt][ct] = MFMA(a_ah[rt], bnl, acc[rt][ct]);
            }
        }
    }
    // epilogue: pre-BN packed hi|lo into pbuf
    int dr = (l >> 4) * 4;
#pragma unroll
    for (int rt = 0; rt < 2; ++rt)
#pragma unroll
        for (int ct = 0; ct < 2; ++ct)
#pragma unroll
            for (int j = 0; j < 4; ++j) {
                float v = acc[rt][ct][j];
                ushort hi = bfh(v);
                ushort lo = bfh(v - bff(hi));
                pbuf[(size_t)(row0 + rt * 16 + dr + j) * 128 + n0 + ct * 16 + lr] =
                    (uint)hi | ((uint)lo << 16);
            }
    // BN column partials from registers
    float s0 = 0.f, q0 = 0.f, s1 = 0.f, q1 = 0.f;
#pragma unroll
    for (int rt = 0; rt < 2; ++rt)
#pragma unroll
        for (int j = 0; j < 4; ++j) {
            float v0 = acc[rt][0][j], v1 = acc[rt][1][j];
            s0 += v0; q0 += v0 * v0;
            s1 += v1; q1 += v1 * v1;
        }
    s0 += __shfl_xor(s0, 16, 64); s0 += __shfl_xor(s0, 32, 64);
    q0 += __shfl_xor(q0, 16, 64); q0 += __shfl_xor(q0, 32, 64);
    s1 += __shfl_xor(s1, 16, 64); s1 += __shfl_xor(s1, 32, 64);
    q1 += __shfl_xor(q1, 16, 64); q1 += __shfl_xor(q1, 32, 64);
    if (l < 16) {
        float* pbp = partials + (size_t)blockIdx.x * 256;
        pbp[n0 + lr] = s0;
        pbp[n0 + 16 + lr] = s1;
        pbp[128 + n0 + lr] = q0;
        pbp[128 + n0 + 16 + lr] = q1;
    }
}

// reduce per-block partials -> stats[256]
__global__ __launch_bounds__(256) void bnred_kernel(const float* __restrict__ partials,
                                                    float* __restrict__ stats, int nblk) {
    float s = 0.f;
    for (int b = blockIdx.x; b < nblk; b += gridDim.x)
        s += partials[(size_t)b * 256 + threadIdx.x];
    atomicAdd(&stats[threadIdx.x], s);
}

// BN finalize+apply+relu: reads packed hi|lo pre-BN, writes post-BN hi/lo bf16
__global__ void bn_apply_kernel(const uint* __restrict__ pb, ushort* __restrict__ xh,
                                ushort* __restrict__ xl, const float* __restrict__ stats,
                                const float* __restrict__ gamma, const float* __restrict__ beta) {
    long long t = (long long)blockIdx.x * blockDim.x + threadIdx.x;
    if (t >= (long long)NODES * 32) return;
    int j4 = ((int)(t & 31)) * 4;
    size_t off = (size_t)(t >> 5) * 128 + j4;
    uint4 u = *reinterpret_cast<const uint4*>(pb + off);
    float4 v;
    v.x = __uint_as_float(u.x << 16) + __uint_as_float(u.x & 0xffff0000u);
    v.y = __uint_as_float(u.y << 16) + __uint_as_float(u.y & 0xffff0000u);
    v.z = __uint_as_float(u.z << 16) + __uint_as_float(u.z & 0xffff0000u);
    v.w = __uint_as_float(u.w << 16) + __uint_as_float(u.w & 0xffff0000u);
    float4 s4 = *reinterpret_cast<const float4*>(stats + j4);
    float4 q4 = *reinterpret_cast<const float4*>(stats + 128 + j4);
    float4 g4 = *reinterpret_cast<const float4*>(gamma + j4);
    float4 be4 = *reinterpret_cast<const float4*>(beta + j4);
    const float inv = 1.0f / NODES;
    float m, var, a;
    m = s4.x * inv; var = q4.x * inv - m * m; a = g4.x * rsqrtf(var + 1e-5f);
    v.x = fmaxf(v.x * a + (be4.x - m * a), 0.f);
    m = s4.y * inv; var = q4.y * inv - m * m; a = g4.y * rsqrtf(var + 1e-5f);
    v.y = fmaxf(v.y * a + (be4.y - m * a), 0.f);
    m = s4.z * inv; var = q4.z * inv - m * m; a = g4.z * rsqrtf(var + 1e-5f);
    v.z = fmaxf(v.z * a + (be4.z - m * a), 0.f);
    m = s4.w * inv; var = q4.w * inv - m * m; a = g4.w * rsqrtf(var + 1e-5f);
    v.w = fmaxf(v.w * a + (be4.w - m * a), 0.f);
    ushort4 hh, ll;
    hh.x = bfh(v.x); hh.y = bfh(v.y); hh.z = bfh(v.z); hh.w = bfh(v.w);
    ll.x = bfh(v.x - bff(hh.x)); ll.y = bfh(v.y - bff(hh.y));
    ll.z = bfh(v.z - bff(hh.z)); ll.w = bfh(v.w - bff(hh.w));
    *reinterpret_cast<ushort4*>(xh + off) = hh;
    *reinterpret_cast<ushort4*>(xl + off) = ll;
}

// ================= GEMM3 + fused log-softmax =================
__global__ __launch_bounds__(256) void gemm3_kernel(
    const ushort* __restrict__ xh, const ushort* __restrict__ xl,
    const ushort* __restrict__ ahb,
    const ushort* __restrict__ Wsh, const ushort* __restrict__ Wsl,
    const ushort* __restrict__ Wnh, const ushort* __restrict__ Wnl,
    float* __restrict__ out) {
    __shared__ ushort xh_s[64 * 128], xl_s[64 * 128], ah_s[64 * 128];
    int t = threadIdx.x;
    int row0 = blockIdx.x * 64;
#pragma unroll
    for (int i = 0; i < 4; ++i) {
        int f = t + i * 256;            // 1024 chunks of 8 shorts
        int r = f >> 4;
        int c0 = (f & 15) * 8;
        int cs = c0 ^ ((r & 7) << 3);
        int rr = row0 + r; if (rr >= NODES) rr = NODES - 1;
        size_t go = (size_t)rr * 128 + c0;
        *reinterpret_cast<uint4*>(&xh_s[r * 128 + cs]) = *reinterpret_cast<const uint4*>(xh + go);
        *reinterpret_cast<uint4*>(&xl_s[r * 128 + cs]) = *reinterpret_cast<const uint4*>(xl + go);
        *reinterpret_cast<uint4*>(&ah_s[r * 128 + cs]) = *reinterpret_cast<const uint4*>(ahb + go);
    }
    __syncthreads();
    int w = t >> 6;
    int l = t & 63;
    int lr = l & 15;
    int kq = (l >> 4) * 8;
    f32x4 acc[3] = {};
#pragma unroll
    for (int kk = 0; kk < 4; ++kk) {
        int kf = kk * 32 + kq;
        int r = w * 16 + lr;
        int ks = kf ^ ((r & 7) << 3);
        bf16x8 a_xh = *reinterpret_cast<const bf16x8*>(&xh_s[r * 128 + ks]);
        bf16x8 a_xl = *reinterpret_cast<const bf16x8*>(&xl_s[r * 128 + ks]);
        bf16x8 a_ah = *reinterpret_cast<const bf16x8*>(&ah_s[r * 128 + ks]);
#pragma unroll
        for (int ct = 0; ct < 3; ++ct) {
            size_t wo = (size_t)(ct * 16 + lr) * 128 + kf;
            bf16x8 bsh = *reinterpret_cast<const bf16x8*>(Wsh + wo);
            bf16x8 bsl = *reinterpret_cast<const bf16x8*>(Wsl + wo);
            bf16x8 bnh = *reinterpret_cast<const bf16x8*>(Wnh + wo);
            bf16x8 bnl = *reinterpret_cast<const bf16x8*>(Wnl + wo);
            acc[ct] = MFMA(a_xh, bsh, acc[ct]);
            acc[ct] = MFMA(a_xh, bsl, acc[ct]);
            acc[ct] = MFMA(a_xl, bsh, acc[ct]);
            acc[ct] = MFMA(a_ah, bnh, acc[ct]);
            acc[ct] = MFMA(a_ah, bnl, acc[ct]);
        }
    }
    int dr = (l >> 4) * 4;
#pragma unroll
    for (int j = 0; j < 4; ++j) {
        float v0 = acc[0][j], v1 = acc[1][j];
        float v2 = (lr < 8) ? acc[2][j] : -INFINITY;
        float m = fmaxf(v0, fmaxf(v1, v2));
#pragma unroll
        for (int o = 8; o; o >>= 1) m = fmaxf(m, __shfl_xor(m, o, 16));
        float e = expf(v0 - m) + expf(v1 - m) + ((lr < 8) ? expf(v2 - m) : 0.f);
#pragma unroll
        for (int o = 8; o; o >>= 1) e += __shfl_xor(e, o, 16);
        float lse = m + logf(e);
        int row = row0 + w * 16 + dr + j;
        if (row < NODES) {
            out[(size_t)row * DOUT + lr] = v0 - lse;
            out[(size_t)row * DOUT + 16 + lr] = v1 - lse;
            if (lr < 8) out[(size_t)row * DOUT + 32 + lr] = acc[2][j] - lse;
        }
    }
}

extern "C" void kernel_launch(void* const* d_in, const int* in_sizes, int n_in,
                              void* d_out, int out_size, void* d_ws, size_t ws_size,
                              hipStream_t stream) {
    const float* feat   = (const float*)d_in[0];
    const float* Ws1    = (const float*)d_in[1];
    const float* Wn1    = (const float*)d_in[2];
    const float* gamma1 = (const float*)d_in[3];
    const float* beta1  = (const float*)d_in[4];
    const float* Ws2    = (const float*)d_in[5];
    const float* Wn2    = (const float*)d_in[6];
    const float* gamma2 = (const float*)d_in[7];
    const float* beta2  = (const float*)d_in[8];
    const float* Ws3    = (const float*)d_in[9];
    const float* Wn3    = (const float*)d_in[10];
    const int*   src    = (const int*)d_in[11];
    const int*   dst    = (const int*)d_in[12];
    float* out = (float*)d_out;

    float* ws = (float*)d_ws;
    const size_t NF = (size_t)NODES * 128;
    uint* pbuf = (uint*)ws;                 // N*128 uint packed pre-BN; aliases ebuf (CSR phase)
    float* stats = ws + NF;                 // 256 f32
    float* partials = stats + 256;          // 3125*256 f32
    ushort* ahb = (ushort*)(partials + 3125 * 256);  // N*128 bf16 neighbor mean
    ushort* xh = ahb + NF;                  // N*128 bf16 hi
    ushort* xl = xh + NF;                   // N*128 bf16 lo
    ushort* Wh = xl + NF;                   // 77824
    ushort* Wl = Wh + 77824;
    int* rowptr = (int*)(Wl + 77824);       // N+1
    uint* ghist = (uint*)(rowptr + NODES + 1);
    uint* hpart = ghist + GH;               // 128
    uint* hpoff = hpart + 128;              // 128
    int* bucket_base = (int*)(hpoff + 128); // NBUCK+1
    int* col    = bucket_base + NBUCK + 1;  // E
    uint2* ebuf = (uint2*)pbuf;             // E uint2 = 12.8MB, dead before layer-1 gemm

    ushort* Wsh1 = Wh;           ushort* Wsl1 = Wl;
    ushort* Wnh1 = Wh + 16384;   ushort* Wnl1 = Wl + 16384;
    ushort* Wsh2 = Wh + 32768;   ushort* Wsl2 = Wl + 32768;
    ushort* Wnh2 = Wh + 49152;   ushort* Wnl2 = Wl + 49152;
    ushort* Wsh3 = Wh + 65536;   ushort* Wsl3 = Wl + 65536;
    ushort* Wnh3 = Wh + 71680;   ushort* Wnl3 = Wl + 71680;

    const int GEMM_GRID  = NODES / 32;           // 3125
    const int GEMM3_GRID = (NODES + 63) / 64;    // 1563
    const int AGG_GRID   = NODES / 4;            // 25000

    // ---- CSR build: bucket sort, LDS atomics only ----
    hist1_kernel<<<HB, 256, 0, stream>>>(dst, ghist);
    hs1_kernel<<<NHS, 512, 0, stream>>>(ghist, hpart);
    hs2_kernel<<<1, 128, 0, stream>>>(hpart, hpoff, rowptr, bucket_base);
    hs3_kernel<<<NHS, 512, 0, stream>>>(ghist, hpoff, bucket_base);
    scatter1_kernel<<<HB, 256, 0, stream>>>(src, dst, ghist, ebuf);
    csr2_kernel<<<NBUCK, 256, 0, stream>>>(ebuf, bucket_base, rowptr, col);

    // ---- weight splits + feat hi/lo split ----
    wsplit_all_kernel<<<304, 256, 0, stream>>>(Ws1, Wn1, Ws2, Wn2, Ws3, Wn3, Wh, Wl);
    fsplit_kernel<<<(int)(NF / 4 / 256), 256, 0, stream>>>(feat, xh, xl);

    // ---- layer 1 ----
    gather_agg_kernel<<<AGG_GRID, 256, 0, stream>>>(xh, rowptr, col, ahb);
    gemm12_kernel<<<GEMM_GRID, 256, 0, stream>>>(xh, xl, ahb, pbuf,
                                                 Wsh1, Wsl1, Wnh1, Wnl1, partials, stats);
    bnred_kernel<<<64, 256, 0, stream>>>(partials, stats, GEMM_GRID);
    bn_apply_kernel<<<(NODES * 32) / 256, 256, 0, stream>>>(pbuf, xh, xl, stats, gamma1, beta1);

    // ---- layer 2 ----
    gather_agg_kernel<<<AGG_GRID, 256, 0, stream>>>(xh, rowptr, col, ahb);
    gemm12_kernel<<<GEMM_GRID, 256, 0, stream>>>(xh, xl, ahb, pbuf,
                                                 Wsh2, Wsl2, Wnh2, Wnl2, partials, stats);
    bnred_kernel<<<64, 256, 0, stream>>>(partials, stats, GEMM_GRID);
    bn_apply_kernel<<<(NODES * 32) / 256, 256, 0, stream>>>(pbuf, xh, xl, stats, gamma2, beta2);

    // ---- layer 3 (+fused log-softmax) ----
    gather_agg_kernel<<<AGG_GRID, 256, 0, stream>>>(xh, rowptr, col, ahb);
    gemm3_kernel<<<GEMM3_GRID, 256, 0, stream>>>(xh, xl, ahb, Wsh3, Wsl3, Wnh3, Wnl3, out);
}